// Round 8
// baseline (1269.367 us; speedup 1.0000x reference)
//
#include <hip/hip_runtime.h>

typedef __bf16 bf16x8 __attribute__((ext_vector_type(8)));
typedef unsigned short us8 __attribute__((ext_vector_type(8)));
typedef float f32x4 __attribute__((ext_vector_type(4)));

#define NROW 32      // rows per workgroup (160 WGs x 32 = 5120)
#define A_STR 136    // ushort stride per h-state row (balanced frag reads)
#define AX_STR 40    // ushort stride per Ax row (balanced: bank 4*(5r+gq) mod 32)
#define WL_STR 521   // us8 stride per (q,gq) frag-row of LDS-resident Whh0 half
#define NSTEP 119

__device__ __forceinline__ unsigned short f2bf(float f){
  unsigned int x = __builtin_bit_cast(unsigned int, f);
  x += 0x7fffu + ((x >> 16) & 1u);          // RNE
  return (unsigned short)(x >> 16);
}
__device__ __forceinline__ float bf2f(unsigned short s){
  unsigned int x = ((unsigned int)s) << 16;
  return __builtin_bit_cast(float, x);
}
__device__ __forceinline__ float sigm(float x){ return 1.0f/(1.0f + __expf(-x)); }
__device__ __forceinline__ float tanh_(float x){ float e = __expf(2.0f*x); return 1.0f - 2.0f/(e + 1.0f); }

__device__ __forceinline__ f32x4 MFMA(us8 a, us8 b, f32x4 c){
  return __builtin_amdgcn_mfma_f32_16x16x32_bf16(
      __builtin_bit_cast(bf16x8, a), __builtin_bit_cast(bf16x8, b), c, 0, 0, 0);
}
// AGPR-resident weight path ("a" forces the B fragment into the accumulator
// file; homes become AGPR, freeing the arch-VGPR half of the unified file).
__device__ __forceinline__ void mfma_ag(f32x4& d, us8 a, us8 b){
  asm("v_mfma_f32_16x16x32_bf16 %0, %1, %2, %0" : "+v"(d) : "v"(a), "a"(b));
}
// fence before VALU reads accumulators last written by asm MFMA
__device__ __forceinline__ void accfence8(f32x4& a0, f32x4& a1, f32x4& a2, f32x4& a3,
                                          f32x4& a4, f32x4& a5, f32x4& a6, f32x4& a7){
  asm("s_nop 7\n\ts_nop 7\n\ts_nop 2"
      : "+v"(a0), "+v"(a1), "+v"(a2), "+v"(a3),
        "+v"(a4), "+v"(a5), "+v"(a6), "+v"(a7));
}

struct SharedMem {
  unsigned short A0[2][NROW*A_STR];     // h0 bf16, double buffered  (17408 B)
  unsigned short A1[2][NROW*A_STR];     // h1 bf16, double buffered  (17408 B)
  unsigned short Ax[2][NROW][AX_STR];   // x-MFMA A operand           (5120 B)
  unsigned short xw[512*8];             // x-MFMA B per gate-col      (8192 B)
  unsigned short W0l[8*WL_STR*8];       // Whh0 k-blocks 0,1 frags   (66688 B)
  float c_lds[2][2][2][256][4];         // c[layer][rt][ct][thr][j]  (32768 B)
  float b1[512];                        //                            (2048 B)
  float Wh2f[256];                      //                            (1024 B)
  float red[NROW][8][2];                //                            (2048 B)
  float we_s[64];
  float be_s[64];
  float bh_s[2];
};  // ~149.6 KB -> 1 WG/CU

// 256 threads = 4 waves = 1 wave/SIMD -> 512 unified regs/wave.
// Split: arch ~220 (WV 64 + WV2 32 + acc 32 + transients), AGPR 224 (+32 slack).
__global__ __launch_bounds__(256)
__attribute__((amdgpu_waves_per_eu(1, 1)))
void deepar_kernel(
    const float* __restrict__ hist, const float* __restrict__ fut,
    const float* __restrict__ We,   const float* __restrict__ be,
    const float* __restrict__ Wih0, const float* __restrict__ Whh0,
    const float* __restrict__ bih0, const float* __restrict__ bhh0,
    const float* __restrict__ Wih1, const float* __restrict__ Whh1,
    const float* __restrict__ bih1, const float* __restrict__ bhh1,
    const float* __restrict__ Wh,   const float* __restrict__ bh,
    float* __restrict__ out)
{
  __shared__ SharedMem S;
  const int tid = threadIdx.x;     // 0..255
  const int wg  = blockIdx.x;
  const int b   = wg / 10;
  const int n0  = (wg % 10) * NROW;
  const int w   = tid >> 6;        // wave 0..3
  const int l   = tid & 63;
  const int gq  = l >> 4;          // k-group 0..3
  const int r   = l & 15;          // row/col within 16-tile
  const int hbase = w * 32;        // h-col base of this wave

  // ---------------- prologue ----------------
  {
    us8 z = {0,0,0,0,0,0,0,0};
    us8* pA0 = (us8*)&S.A0[0][0];
    us8* pA1 = (us8*)&S.A1[0][0];
    for (int i = tid; i < 2*NROW*A_STR/8; i += 256){ pA0[i] = z; pA1[i] = z; }
    us8* pAx = (us8*)&S.Ax[0][0][0];
    for (int i = tid; i < 2*NROW*AX_STR/8; i += 256) pAx[i] = z;
    f32x4 zf = {0.f,0.f,0.f,0.f};
    #pragma unroll
    for (int q = 0; q < 8; ++q) *(f32x4*)&S.c_lds[q >> 2][(q >> 1) & 1][q & 1][tid][0] = zf;
  }
  S.Wh2f[tid] = Wh[tid];
  if (tid < 64)       S.we_s[tid]       = We[tid];
  else if (tid < 128) S.be_s[tid - 64]  = be[tid - 64];
  else if (tid < 130) S.bh_s[tid - 128] = bh[tid - 128];
  __syncthreads();

  // per-col x weights: u = Wih0[:,:64]@We ; v = ..@be + bih0 + bhh0
  for (int cc = tid; cc < 512; cc += 256){
    const float* wr = Wih0 + cc * 68;
    float u = 0.f, v = 0.f;
    #pragma unroll 8
    for (int e = 0; e < 64; ++e){
      float wv = wr[e];
      u = fmaf(wv, S.we_s[e], u);
      v = fmaf(wv, S.be_s[e], v);
    }
    v += bih0[cc] + bhh0[cc];
    unsigned short* xp = &S.xw[cc * 8];
    xp[0] = f2bf(u);
    xp[1] = f2bf(wr[64]); xp[2] = f2bf(wr[65]); xp[3] = f2bf(wr[66]); xp[4] = f2bf(wr[67]);
    xp[5] = f2bf(v);
    xp[6] = 0; xp[7] = 0;
    S.b1[cc] = bih1[cc] + bhh1[cc];
  }
  // Whh0 k-blocks 0,1 -> LDS fragments: entry (qgq, col) = Whh0[col][qgq*8 .. +8]
  for (int idx = tid; idx < 8*512; idx += 256){
    int qgq = idx >> 9, col = idx & 511;
    const float* p = Whh0 + col*128 + qgq*8;
    f32x4 x0 = *(const f32x4*)p;
    f32x4 x1 = *(const f32x4*)(p + 4);
    us8 tt;
    tt[0]=f2bf(x0[0]); tt[1]=f2bf(x0[1]); tt[2]=f2bf(x0[2]); tt[3]=f2bf(x0[3]);
    tt[4]=f2bf(x1[0]); tt[5]=f2bf(x1[1]); tt[6]=f2bf(x1[2]); tt[7]=f2bf(x1[3]);
    *(us8*)&S.W0l[(qgq*WL_STR + col)*8] = tt;
  }
  // Ax constant-one column (k=5), both buffers
  if (tid < 64){ int row = tid >> 1, bsel = tid & 1; S.Ax[bsel][row][5] = 0x3F80; }
  // stage step-0 scalars: tgt tau=0, cov tau=1 -> Ax[0]
  if (tid < 160){
    int srow, sch, tau;
    if (tid < 32){ srow = tid; sch = 0; tau = 0; }
    else { int k = tid - 32; srow = k >> 2; sch = 1 + (k & 3); tau = 1; }
    const float* p = hist + ((b*96 + tau)*320 + n0 + srow)*5;
    S.Ax[0][srow][sch] = f2bf(p[sch]);
  }

  // register weights:
  //   WV  (VGPR): Whh0 k-blocks 2,3       -> [g][ct][qq]   (64 regs)
  //   WV2 (VGPR): Whh1 k-block 3          -> [g][ct]       (32 regs)
  //   WA1 (AGPR): Wih1 all k              -> [g][ct][q]    (128 regs)
  //   WA2 (AGPR): Whh1 k-blocks 0..2      -> [g][ct][q]    (96 regs)
  us8 WV[4][2][2], WV2[4][2], WA1[4][2][4], WA2[4][2][3];
  #pragma unroll
  for (int m = 0; m < 3; ++m){
    const float* base = (m == 0) ? Whh0 : (m == 1) ? Wih1 : Whh1;
    #pragma unroll
    for (int g = 0; g < 4; ++g){
      #pragma unroll
      for (int ct = 0; ct < 2; ++ct){
        int col = g*128 + hbase + ct*16 + r;
        #pragma unroll
        for (int q = 0; q < 4; ++q){
          if (m == 0 && q < 2) continue;        // LDS-resident half
          const float* p = base + col*128 + q*32 + gq*8;
          f32x4 x0 = *(const f32x4*)p;
          f32x4 x1 = *(const f32x4*)(p + 4);
          us8 tt;
          tt[0]=f2bf(x0[0]); tt[1]=f2bf(x0[1]); tt[2]=f2bf(x0[2]); tt[3]=f2bf(x0[3]);
          tt[4]=f2bf(x1[0]); tt[5]=f2bf(x1[1]); tt[6]=f2bf(x1[2]); tt[7]=f2bf(x1[3]);
          if (m == 0)            WV[g][ct][q-2] = tt;
          else if (m == 1)       WA1[g][ct][q]  = tt;
          else if (q < 3)        WA2[g][ct][q]  = tt;
          else                   WV2[g][ct]     = tt;
        }
      }
    }
  }

  __syncthreads();

  // ---------------- time loop ----------------
  for (int t = 0; t < NSTEP; ++t){
    const int pb = t & 1, nb = pb ^ 1;
    const unsigned short* A0r = S.A0[pb];
    unsigned short*       A0w = S.A0[nb];
    const unsigned short* A1r = S.A1[pb];
    unsigned short*       A1w = S.A1[nb];

    // prefetch next-step scalars (hide HBM latency under both MFMA phases)
    float stv = 0.f; int sto = -1;
    if (t + 1 < NSTEP && tid < 160){
      int srow, sch, tau;
      if (tid < 32){ srow = tid; sch = 0; tau = t + 1; }
      else { int k = tid - 32; srow = k >> 2; sch = 1 + (k & 3); tau = t + 2; }
      const float* p = (tau < 96) ? (hist + ((b*96 + tau)*320 + n0 + srow)*5)
                                  : (fut  + ((b*24 + (tau - 96))*320 + n0 + srow)*5);
      stv = p[sch];
      sto = nb*NROW*AX_STR + srow*AX_STR + sch;
    }

    // ---- layer 0: gates = x-MFMA + h0 @ Whh0^T (k0,k1 from LDS; k2,k3 regs) ----
    #pragma unroll
    for (int rt = 0; rt < 2; ++rt){
      const int rbase = rt * 16;
      f32x4 acc[4][2];
      us8 ax = *(const us8*)&S.Ax[pb][rbase + r][gq*8];
      #pragma unroll
      for (int g = 0; g < 4; ++g)
        #pragma unroll
        for (int ct = 0; ct < 2; ++ct){
          us8 bx = *(const us8*)&S.xw[(g*128 + hbase + ct*16 + r)*8];
          f32x4 z = {0.f,0.f,0.f,0.f};
          acc[g][ct] = MFMA(ax, bx, z);
        }
      #pragma unroll
      for (int q = 0; q < 2; ++q){
        us8 a = *(const us8*)&A0r[(rbase + r)*A_STR + q*32 + gq*8];
        #pragma unroll
        for (int g = 0; g < 4; ++g)
          #pragma unroll
          for (int ct = 0; ct < 2; ++ct){
            us8 bw = *(const us8*)&S.W0l[((q*4 + gq)*WL_STR + g*128 + hbase + ct*16 + r)*8];
            acc[g][ct] = MFMA(a, bw, acc[g][ct]);
          }
      }
      #pragma unroll
      for (int q = 2; q < 4; ++q){
        us8 a = *(const us8*)&A0r[(rbase + r)*A_STR + q*32 + gq*8];
        #pragma unroll
        for (int g = 0; g < 4; ++g)
          #pragma unroll
          for (int ct = 0; ct < 2; ++ct)
            acc[g][ct] = MFMA(a, WV[g][ct][q-2], acc[g][ct]);
      }
      f32x4 cpr[2], cn[2];
      cpr[0] = *(const f32x4*)&S.c_lds[0][rt][0][tid][0];
      cpr[1] = *(const f32x4*)&S.c_lds[0][rt][1][tid][0];
      #pragma unroll
      for (int ct = 0; ct < 2; ++ct)
        #pragma unroll
        for (int j = 0; j < 4; ++j){
          float c = fmaf(sigm(acc[1][ct][j]), cpr[ct][j],
                         sigm(acc[0][ct][j]) * tanh_(acc[2][ct][j]));
          cn[ct][j] = c;
          float h = sigm(acc[3][ct][j]) * tanh_(c);
          A0w[(rbase + gq*4 + j)*A_STR + hbase + ct*16 + r] = f2bf(h);
        }
      *(f32x4*)&S.c_lds[0][rt][0][tid][0] = cn[0];
      *(f32x4*)&S.c_lds[0][rt][1][tid][0] = cn[1];
    }
    __syncthreads();   // B1: new h0 visible

    // ---- layer 1: gates = b1 + h0new @ Wih1^T + h1 @ Whh1^T ----
    #pragma unroll
    for (int rt = 0; rt < 2; ++rt){
      const int rbase = rt * 16;
      f32x4 acc[4][2];
      // init + intrinsic-first (Whh1 k3): compiler handles VALU->MFMA hazards
      us8 a13 = *(const us8*)&A1r[(rbase + r)*A_STR + 3*32 + gq*8];
      #pragma unroll
      for (int g = 0; g < 4; ++g)
        #pragma unroll
        for (int ct = 0; ct < 2; ++ct){
          float bv = S.b1[g*128 + hbase + ct*16 + r];
          f32x4 iv = {bv, bv, bv, bv};
          acc[g][ct] = MFMA(a13, WV2[g][ct], iv);
        }
      #pragma unroll
      for (int q = 0; q < 4; ++q){
        us8 a = *(const us8*)&A0w[(rbase + r)*A_STR + q*32 + gq*8];
        #pragma unroll
        for (int g = 0; g < 4; ++g)
          #pragma unroll
          for (int ct = 0; ct < 2; ++ct)
            mfma_ag(acc[g][ct], a, WA1[g][ct][q]);
      }
      #pragma unroll
      for (int q = 0; q < 3; ++q){
        us8 a = *(const us8*)&A1r[(rbase + r)*A_STR + q*32 + gq*8];
        #pragma unroll
        for (int g = 0; g < 4; ++g)
          #pragma unroll
          for (int ct = 0; ct < 2; ++ct)
            mfma_ag(acc[g][ct], a, WA2[g][ct][q]);
      }
      accfence8(acc[0][0], acc[0][1], acc[1][0], acc[1][1],
                acc[2][0], acc[2][1], acc[3][0], acc[3][1]);
      f32x4 cpr[2], cn[2];
      cpr[0] = *(const f32x4*)&S.c_lds[1][rt][0][tid][0];
      cpr[1] = *(const f32x4*)&S.c_lds[1][rt][1][tid][0];
      #pragma unroll
      for (int ct = 0; ct < 2; ++ct)
        #pragma unroll
        for (int j = 0; j < 4; ++j){
          float c = fmaf(sigm(acc[1][ct][j]), cpr[ct][j],
                         sigm(acc[0][ct][j]) * tanh_(acc[2][ct][j]));
          cn[ct][j] = c;
          float h = sigm(acc[3][ct][j]) * tanh_(c);
          A1w[(rbase + gq*4 + j)*A_STR + hbase + ct*16 + r] = f2bf(h);
        }
      *(f32x4*)&S.c_lds[1][rt][0][tid][0] = cn[0];
      *(f32x4*)&S.c_lds[1][rt][1][tid][0] = cn[1];
    }
    if (sto >= 0) ((unsigned short*)&S.Ax[0][0][0])[sto] = f2bf(stv);
    __syncthreads();   // B2: new h1 + next-step Ax visible

    // ---- head: only last 24 steps ----
    if (t >= 95){
      const int rown = tid >> 3, cg = tid & 7;   // 1 row x 16 h-cols per thread
      us8 hv0 = *(const us8*)&A1w[rown*A_STR + cg*16];
      us8 hv1 = *(const us8*)&A1w[rown*A_STR + cg*16 + 8];
      float pm = 0.f, ps = 0.f;
      #pragma unroll
      for (int k = 0; k < 8; ++k){
        float ha = bf2f(hv0[k]); ha = ha > 0.f ? ha : 0.f;
        float hb = bf2f(hv1[k]); hb = hb > 0.f ? hb : 0.f;
        pm = fmaf(ha, S.Wh2f[cg*16 + k], pm);
        pm = fmaf(hb, S.Wh2f[cg*16 + 8 + k], pm);
        ps = fmaf(ha, S.Wh2f[128 + cg*16 + k], ps);
        ps = fmaf(hb, S.Wh2f[128 + cg*16 + 8 + k], ps);
      }
      S.red[rown][cg][0] = pm; S.red[rown][cg][1] = ps;
      __syncthreads(); // B3 (uniform: t is uniform)
      if (tid < 64){
        int row = tid >> 1, o = tid & 1;
        float s = S.bh_s[o];
        #pragma unroll
        for (int k = 0; k < 8; ++k) s += S.red[row][k][o];
        if (o) s = (s > 15.f) ? s : __logf(1.0f + __expf(s));
        out[((b*24 + (t - 95))*320 + (n0 + row))*2 + o] = s;
      }
    }
  }
}

extern "C" void kernel_launch(void* const* d_in, const int* in_sizes, int n_in,
                              void* d_out, int out_size, void* d_ws, size_t ws_size,
                              hipStream_t stream) {
  const float* hist = (const float*)d_in[0];
  const float* fut  = (const float*)d_in[1];
  const float* We   = (const float*)d_in[2];
  const float* be   = (const float*)d_in[3];
  const float* Wih0 = (const float*)d_in[4];
  const float* Whh0 = (const float*)d_in[5];
  const float* bih0 = (const float*)d_in[6];
  const float* bhh0 = (const float*)d_in[7];
  const float* Wih1 = (const float*)d_in[8];
  const float* Whh1 = (const float*)d_in[9];
  const float* bih1 = (const float*)d_in[10];
  const float* bhh1 = (const float*)d_in[11];
  const float* Wh   = (const float*)d_in[12];
  const float* bh   = (const float*)d_in[13];
  float* out = (float*)d_out;

  deepar_kernel<<<dim3(160), dim3(256), 0, stream>>>(
      hist, fut, We, be, Wih0, Whh0, bih0, bhh0,
      Wih1, Whh1, bih1, bhh1, Wh, bh, out);
}

// Round 9
// 1106.952 us; speedup vs baseline: 1.1467x; 1.1467x over previous
//
#include <hip/hip_runtime.h>

typedef __bf16 bf16x8 __attribute__((ext_vector_type(8)));
typedef unsigned short us8 __attribute__((ext_vector_type(8)));
typedef float f32x4 __attribute__((ext_vector_type(4)));

#define NROW 32      // rows per workgroup (160 WGs x 32 = 5120)
#define A_STR 136    // ushort stride per h row: 136*2/16=17 ≡ 1 mod 8 -> optimal b128 spread
#define AX_STR 40    // ushort stride per Ax row: 5r+gq spread
#define WL_STR 521   // 16B-units per frag-row of LDS Whh0 half: 521 ≡ 1 mod 8 -> optimal
#define NSTEP 119

__device__ __forceinline__ unsigned short f2bf(float f){
  unsigned int x = __builtin_bit_cast(unsigned int, f);
  x += 0x7fffu + ((x >> 16) & 1u);          // RNE
  return (unsigned short)(x >> 16);
}
__device__ __forceinline__ float bf2f(unsigned short s){
  unsigned int x = ((unsigned int)s) << 16;
  return __builtin_bit_cast(float, x);
}
__device__ __forceinline__ float sigm(float x){ return 1.0f/(1.0f + __expf(-x)); }
__device__ __forceinline__ float tanh_(float x){ float e = __expf(2.0f*x); return 1.0f - 2.0f/(e + 1.0f); }

__device__ __forceinline__ f32x4 MFMA(us8 a, us8 b, f32x4 c){
  return __builtin_amdgcn_mfma_f32_16x16x32_bf16(
      __builtin_bit_cast(bf16x8, a), __builtin_bit_cast(bf16x8, b), c, 0, 0, 0);
}
// AGPR-pinned weight MFMA (v7/v8-proven: kills spill of the weight array)
__device__ __forceinline__ void mfma_ag_first(f32x4& d, us8 a, us8 b){
  asm("s_nop 1\n\tv_mfma_f32_16x16x32_bf16 %0, %1, %2, %0" : "+v"(d) : "v"(a), "a"(b));
}
__device__ __forceinline__ void mfma_ag(f32x4& d, us8 a, us8 b){
  asm("v_mfma_f32_16x16x32_bf16 %0, %1, %2, %0" : "+v"(d) : "v"(a), "a"(b));
}
__device__ __forceinline__ void accfence4(f32x4& a0, f32x4& a1, f32x4& a2, f32x4& a3){
  asm("s_nop 7\n\ts_nop 7\n\ts_nop 2"
      : "+v"(a0), "+v"(a1), "+v"(a2), "+v"(a3));
}

struct SharedMem {
  unsigned short A0[2][NROW*A_STR];     // h0 bf16, double buffered  (17408 B)
  unsigned short A1[2][NROW*A_STR];     // h1 bf16, double buffered  (17408 B)
  unsigned short Ax[2][NROW][AX_STR];   // x-MFMA A operand           (5120 B)
  unsigned short xw[512*8];             // x-MFMA B per gate-col      (8192 B)
  unsigned short W0l[8*WL_STR*8];       // Whh0 k-blocks 0,1 frags   (66688 B)
  float c_lds[2][2][512][4];            // c[layer][rt][tid][j]      (32768 B)
  float b1[512];                        //                            (2048 B)
  float Wh2f[256];                      //                            (1024 B)
  float red[NROW][16][2];               //                            (4096 B)
  float we_s[64];
  float be_s[64];
  float bh_s[2];
};  // ~152 KB -> 1 WG/CU; 8 waves -> 2 waves/SIMD

// 512 threads = 8 waves = 2/SIMD. Budget per wave: 128 arch + 128 AGPR.
// AGPR: Wih1(16 frags) + Whh1(16 frags) = 128. Arch: Whh0-hi 32 + acc 16 + ~70.
__global__ __launch_bounds__(512)
__attribute__((amdgpu_waves_per_eu(2, 2)))
void deepar_kernel(
    const float* __restrict__ hist, const float* __restrict__ fut,
    const float* __restrict__ We,   const float* __restrict__ be,
    const float* __restrict__ Wih0, const float* __restrict__ Whh0,
    const float* __restrict__ bih0, const float* __restrict__ bhh0,
    const float* __restrict__ Wih1, const float* __restrict__ Whh1,
    const float* __restrict__ bih1, const float* __restrict__ bhh1,
    const float* __restrict__ Wh,   const float* __restrict__ bh,
    float* __restrict__ out)
{
  __shared__ SharedMem S;
  const int tid = threadIdx.x;     // 0..511
  const int wg  = blockIdx.x;
  const int b   = wg / 10;
  const int n0  = (wg % 10) * NROW;
  const int w   = tid >> 6;        // wave 0..7
  const int l   = tid & 63;
  const int gq  = l >> 4;          // k-group 0..3
  const int r   = l & 15;          // row/col within 16-tile
  const int cw  = w * 16;          // h-col base of this wave (16 cols/wave, gate-aligned)

  // ---------------- prologue ----------------
  {
    us8 z = {0,0,0,0,0,0,0,0};
    us8* pA0 = (us8*)&S.A0[0][0];
    us8* pA1 = (us8*)&S.A1[0][0];
    for (int i = tid; i < 2*NROW*A_STR/8; i += 512){ pA0[i] = z; pA1[i] = z; }
    us8* pAx = (us8*)&S.Ax[0][0][0];
    for (int i = tid; i < 2*NROW*AX_STR/8; i += 512) pAx[i] = z;
    f32x4 zf = {0.f,0.f,0.f,0.f};
    #pragma unroll
    for (int q = 0; q < 4; ++q) *(f32x4*)&S.c_lds[q >> 1][q & 1][tid][0] = zf;
  }
  if (tid < 64)       S.we_s[tid]       = We[tid];
  else if (tid < 128) S.be_s[tid - 64]  = be[tid - 64];
  else if (tid < 384) S.Wh2f[tid - 128] = Wh[tid - 128];
  else if (tid < 386) S.bh_s[tid - 384] = bh[tid - 384];
  __syncthreads();

  // per-col x weights: u = Wih0[:,:64]@We ; v = ..@be + bih0 + bhh0
  {
    const float* wr = Wih0 + tid * 68;
    float u = 0.f, v = 0.f;
    #pragma unroll 8
    for (int e = 0; e < 64; ++e){
      float wv = wr[e];
      u = fmaf(wv, S.we_s[e], u);
      v = fmaf(wv, S.be_s[e], v);
    }
    v += bih0[tid] + bhh0[tid];
    unsigned short* xp = &S.xw[tid * 8];
    xp[0] = f2bf(u);
    xp[1] = f2bf(wr[64]); xp[2] = f2bf(wr[65]); xp[3] = f2bf(wr[66]); xp[4] = f2bf(wr[67]);
    xp[5] = f2bf(v);
    xp[6] = 0; xp[7] = 0;
    S.b1[tid] = bih1[tid] + bhh1[tid];
  }
  // Whh0 k-blocks 0,1 -> LDS frags: row qgq=4q+gq (0..7), col; src = Whh0[col][qgq*8..+8]
  for (int idx = tid; idx < 8*512; idx += 512){
    int qgq = idx >> 9, col = idx & 511;
    const float* p = Whh0 + col*128 + qgq*8;
    f32x4 x0 = *(const f32x4*)p;
    f32x4 x1 = *(const f32x4*)(p + 4);
    us8 tt;
    tt[0]=f2bf(x0[0]); tt[1]=f2bf(x0[1]); tt[2]=f2bf(x0[2]); tt[3]=f2bf(x0[3]);
    tt[4]=f2bf(x1[0]); tt[5]=f2bf(x1[1]); tt[6]=f2bf(x1[2]); tt[7]=f2bf(x1[3]);
    *(us8*)&S.W0l[(qgq*WL_STR + col)*8] = tt;
  }
  // Ax constant-one column (k=5), both buffers
  if (tid < 64){ int row = tid >> 1, bsel = tid & 1; S.Ax[bsel][row][5] = 0x3F80; }
  // stage step-0 scalars: tgt tau=0, cov tau=1 -> Ax[0]
  if (tid < 160){
    int srow, sch, tau;
    if (tid < 32){ srow = tid; sch = 0; tau = 0; }
    else { int k = tid - 32; srow = k >> 2; sch = 1 + (k & 3); tau = 1; }
    const float* p = hist + ((b*96 + tau)*320 + n0 + srow)*5;
    S.Ax[0][srow][sch] = f2bf(p[sch]);
  }

  // register weights (per wave, 16 gate-cols g*128+cw+r):
  //   WV  (arch):  Whh0 k2,k3  [g][q-2]  8 frags = 32 regs
  //   WA1 (AGPR):  Wih1 all k  [g][q]   16 frags = 64 regs
  //   WA2 (AGPR):  Whh1 all k  [g][q]   16 frags = 64 regs
  us8 WV[4][2], WA1[4][4], WA2[4][4];
  #pragma unroll
  for (int m = 0; m < 3; ++m){
    const float* base = (m == 0) ? Whh0 : (m == 1) ? Wih1 : Whh1;
    #pragma unroll
    for (int g = 0; g < 4; ++g){
      int col = g*128 + cw + r;
      #pragma unroll
      for (int q = 0; q < 4; ++q){
        if (m == 0 && q < 2) continue;    // LDS-resident half
        const float* p = base + col*128 + q*32 + gq*8;
        f32x4 x0 = *(const f32x4*)p;
        f32x4 x1 = *(const f32x4*)(p + 4);
        us8 tt;
        tt[0]=f2bf(x0[0]); tt[1]=f2bf(x0[1]); tt[2]=f2bf(x0[2]); tt[3]=f2bf(x0[3]);
        tt[4]=f2bf(x1[0]); tt[5]=f2bf(x1[1]); tt[6]=f2bf(x1[2]); tt[7]=f2bf(x1[3]);
        if (m == 0)      WV[g][q-2] = tt;
        else if (m == 1) WA1[g][q]  = tt;
        else             WA2[g][q]  = tt;
      }
    }
  }

  __syncthreads();

  float b1g[4];
  #pragma unroll
  for (int g = 0; g < 4; ++g) b1g[g] = S.b1[g*128 + cw + r];

  // ---------------- time loop ----------------
  for (int t = 0; t < NSTEP; ++t){
    const int pb = t & 1, nb = pb ^ 1;
    const unsigned short* A0r = S.A0[pb];
    unsigned short*       A0w = S.A0[nb];
    const unsigned short* A1r = S.A1[pb];
    unsigned short*       A1w = S.A1[nb];

    // prefetch next-step scalars (latency hidden under both layers)
    float stv = 0.f; int sto = -1;
    if (t + 1 < NSTEP && tid < 160){
      int srow, sch, tau;
      if (tid < 32){ srow = tid; sch = 0; tau = t + 1; }
      else { int k = tid - 32; srow = k >> 2; sch = 1 + (k & 3); tau = t + 2; }
      const float* p = (tau < 96) ? (hist + ((b*96 + tau)*320 + n0 + srow)*5)
                                  : (fut  + ((b*24 + (tau - 96))*320 + n0 + srow)*5);
      stv = p[sch];
      sto = nb*NROW*AX_STR + srow*AX_STR + sch;
    }

    // ---- layer 0 (intrinsic): gates = x-MFMA + h0 @ Whh0^T ----
    #pragma unroll
    for (int rt = 0; rt < 2; ++rt){
      const int rbase = rt * 16;
      f32x4 acc[4];
      us8 ax = *(const us8*)&S.Ax[pb][rbase + r][gq*8];
      #pragma unroll
      for (int g = 0; g < 4; ++g){
        us8 bx = *(const us8*)&S.xw[(g*128 + cw + r)*8];
        f32x4 z = {0.f,0.f,0.f,0.f};
        acc[g] = MFMA(ax, bx, z);
      }
      #pragma unroll
      for (int q = 0; q < 2; ++q){
        us8 a = *(const us8*)&A0r[(rbase + r)*A_STR + q*32 + gq*8];
        #pragma unroll
        for (int g = 0; g < 4; ++g){
          us8 bw = *(const us8*)&S.W0l[((q*4 + gq)*WL_STR + g*128 + cw + r)*8];
          acc[g] = MFMA(a, bw, acc[g]);
        }
      }
      #pragma unroll
      for (int q = 2; q < 4; ++q){
        us8 a = *(const us8*)&A0r[(rbase + r)*A_STR + q*32 + gq*8];
        #pragma unroll
        for (int g = 0; g < 4; ++g)
          acc[g] = MFMA(a, WV[g][q-2], acc[g]);
      }
      f32x4 cprev = *(const f32x4*)&S.c_lds[0][rt][tid][0];
      f32x4 cnew;
      #pragma unroll
      for (int j = 0; j < 4; ++j){
        float c = fmaf(sigm(acc[1][j]), cprev[j], sigm(acc[0][j]) * tanh_(acc[2][j]));
        cnew[j] = c;
        float h = sigm(acc[3][j]) * tanh_(c);
        A0w[(rbase + gq*4 + j)*A_STR + cw + r] = f2bf(h);
      }
      *(f32x4*)&S.c_lds[0][rt][tid][0] = cnew;
    }
    __syncthreads();   // B1: new h0 visible

    // ---- layer 1 (AGPR asm): gates = b1 + h0new @ Wih1^T + h1 @ Whh1^T ----
    #pragma unroll
    for (int rt = 0; rt < 2; ++rt){
      const int rbase = rt * 16;
      f32x4 acc[4];
      #pragma unroll
      for (int g = 0; g < 4; ++g){
        f32x4 iv = {b1g[g], b1g[g], b1g[g], b1g[g]};
        acc[g] = iv;
      }
      {
        us8 a = *(const us8*)&A0w[(rbase + r)*A_STR + 0*32 + gq*8];
        mfma_ag_first(acc[0], a, WA1[0][0]);
        mfma_ag(acc[1], a, WA1[1][0]);
        mfma_ag(acc[2], a, WA1[2][0]);
        mfma_ag(acc[3], a, WA1[3][0]);
      }
      #pragma unroll
      for (int q = 1; q < 4; ++q){
        us8 a = *(const us8*)&A0w[(rbase + r)*A_STR + q*32 + gq*8];
        #pragma unroll
        for (int g = 0; g < 4; ++g) mfma_ag(acc[g], a, WA1[g][q]);
      }
      #pragma unroll
      for (int q = 0; q < 4; ++q){
        us8 a = *(const us8*)&A1r[(rbase + r)*A_STR + q*32 + gq*8];
        #pragma unroll
        for (int g = 0; g < 4; ++g) mfma_ag(acc[g], a, WA2[g][q]);
      }
      accfence4(acc[0], acc[1], acc[2], acc[3]);
      f32x4 cprev = *(const f32x4*)&S.c_lds[1][rt][tid][0];
      f32x4 cnew;
      #pragma unroll
      for (int j = 0; j < 4; ++j){
        float c = fmaf(sigm(acc[1][j]), cprev[j], sigm(acc[0][j]) * tanh_(acc[2][j]));
        cnew[j] = c;
        float h = sigm(acc[3][j]) * tanh_(c);
        A1w[(rbase + gq*4 + j)*A_STR + cw + r] = f2bf(h);
      }
      *(f32x4*)&S.c_lds[1][rt][tid][0] = cnew;
    }
    if (sto >= 0) ((unsigned short*)&S.Ax[0][0][0])[sto] = f2bf(stv);
    __syncthreads();   // B2: new h1 + next-step Ax visible

    // ---- head: only last 24 steps ----
    if (t >= 95){
      const int rown = tid >> 4, cg = tid & 15;   // 1 row x 8 h-cols per thread
      us8 hv = *(const us8*)&A1w[rown*A_STR + cg*8];
      f32x4 wA0 = *(const f32x4*)&S.Wh2f[cg*8];
      f32x4 wA1v = *(const f32x4*)&S.Wh2f[cg*8 + 4];
      f32x4 wB0 = *(const f32x4*)&S.Wh2f[128 + cg*8];
      f32x4 wB1 = *(const f32x4*)&S.Wh2f[128 + cg*8 + 4];
      float pm = 0.f, ps = 0.f;
      #pragma unroll
      for (int k = 0; k < 4; ++k){
        float h0v = bf2f(hv[k]);     h0v = h0v > 0.f ? h0v : 0.f;
        float h1v = bf2f(hv[4 + k]); h1v = h1v > 0.f ? h1v : 0.f;
        pm = fmaf(h0v, wA0[k], pm);  pm = fmaf(h1v, wA1v[k], pm);
        ps = fmaf(h0v, wB0[k], ps);  ps = fmaf(h1v, wB1[k], ps);
      }
      S.red[rown][cg][0] = pm; S.red[rown][cg][1] = ps;
      __syncthreads(); // B3 (uniform: t is uniform)
      if (tid < 64){
        int row = tid >> 1, o = tid & 1;
        float s = S.bh_s[o];
        #pragma unroll
        for (int k = 0; k < 16; ++k) s += S.red[row][k][o];
        if (o) s = (s > 15.f) ? s : __logf(1.0f + __expf(s));
        out[((b*24 + (t - 95))*320 + (n0 + row))*2 + o] = s;
      }
    }
  }
}

extern "C" void kernel_launch(void* const* d_in, const int* in_sizes, int n_in,
                              void* d_out, int out_size, void* d_ws, size_t ws_size,
                              hipStream_t stream) {
  const float* hist = (const float*)d_in[0];
  const float* fut  = (const float*)d_in[1];
  const float* We   = (const float*)d_in[2];
  const float* be   = (const float*)d_in[3];
  const float* Wih0 = (const float*)d_in[4];
  const float* Whh0 = (const float*)d_in[5];
  const float* bih0 = (const float*)d_in[6];
  const float* bhh0 = (const float*)d_in[7];
  const float* Wih1 = (const float*)d_in[8];
  const float* Whh1 = (const float*)d_in[9];
  const float* bih1 = (const float*)d_in[10];
  const float* bhh1 = (const float*)d_in[11];
  const float* Wh   = (const float*)d_in[12];
  const float* bh   = (const float*)d_in[13];
  float* out = (float*)d_out;

  deepar_kernel<<<dim3(160), dim3(512), 0, stream>>>(
      hist, fut, We, be, Wih0, Whh0, bih0, bhh0,
      Wih1, Whh1, bih1, bhh1, Wh, bh, out);
}